// Round 1
// 2205.455 us; speedup vs baseline: 1.3465x; 1.3465x over previous
//
#include <hip/hip_runtime.h>
#include <hip/hip_bf16.h>

// ---------------------------------------------------------------------------
// 3-layer BERT-ish encoder forward on MI355X (gfx950).
// This revision upgrades all matmuls to the verified m97 GEMM structure:
//   128x128 tile (128x64 for A@V), BK=64, 256 threads = 4 waves,
//   bf16 operands staged via __builtin_amdgcn_global_load_lds (16B),
//   mfma_f32_16x16x32_bf16, fp32 accum, fp32-or-bf16 epilogue.
// Activations flow as bf16 (same rounding point as before -> bit-identical):
//   embed/add_ln write fp32 x (residual/LN precision) + bf16 xb (GEMM operand)
//   qkv / attn@V out / gelu(ffn1) written bf16 directly by the GEMM epilogue
//   weights pre-converted to bf16 once per launch (~19 MB)
// Attention weights (an output) stay fp32; A@V uses an fp32-A staging variant.
// ---------------------------------------------------------------------------

typedef __bf16 bf16_t;
typedef __bf16 bf16x4 __attribute__((ext_vector_type(4)));
typedef __bf16 bf16x8 __attribute__((ext_vector_type(8)));
typedef float  f32x4  __attribute__((ext_vector_type(4)));

__device__ __forceinline__ void gld16(const bf16_t* g, bf16_t* l) {
    // direct global->LDS, 16 bytes/lane; LDS dest is wave-uniform base + lane*16
    __builtin_amdgcn_global_load_lds((const __attribute__((address_space(1))) void*)g,
                                     (__attribute__((address_space(3))) void*)l, 16, 0, 0);
}

// ---------------------------------------------------------------------------
// fp32 -> bf16 bulk convert (weights). One float4 -> bf16x4 per thread.
// ---------------------------------------------------------------------------
__global__ __launch_bounds__(256) void cvt_bf16(
    const float* __restrict__ s, bf16_t* __restrict__ d)
{
    int g = blockIdx.x * 256 + threadIdx.x;
    float4 v = ((const float4*)s)[g];
    bf16x4 p;
    p[0] = (bf16_t)v.x; p[1] = (bf16_t)v.y; p[2] = (bf16_t)v.z; p[3] = (bf16_t)v.w;
    ((bf16x4*)d)[g] = p;
}

// ---------------------------------------------------------------------------
// Embedding: x[t] = emb[ids[t]] + pos_emb[t % 512]; also writes bf16 copy.
// ---------------------------------------------------------------------------
__global__ __launch_bounds__(256) void embed_kernel(
    const int* __restrict__ ids, const float* __restrict__ emb,
    const float* __restrict__ pos, float* __restrict__ x, bf16_t* __restrict__ xb)
{
    int g = blockIdx.x * 256 + threadIdx.x;        // float4 units
    int token = g >> 7, c4 = g & 127;
    int id = ids[token];
    float4 e = ((const float4*)emb)[(long long)id * 128 + c4];
    float4 p = ((const float4*)pos)[(long long)(token & 511) * 128 + c4];
    e.x += p.x; e.y += p.y; e.z += p.z; e.w += p.w;
    ((float4*)x)[g] = e;
    bf16x4 h;
    h[0] = (bf16_t)e.x; h[1] = (bf16_t)e.y; h[2] = (bf16_t)e.z; h[3] = (bf16_t)e.w;
    ((bf16x4*)xb)[g] = h;
}

// ---------------------------------------------------------------------------
// m97-style GEMM: C = alpha * A (MxK) * B^T (B is [N,K] bf16) + bias.
// BM=128 fixed, BN in {128,64}. BK=64. 256 threads = 4 waves.
//   BN=128: waves in 2x2, each computes 64x64 (acc[4][4])
//   BN=64 : waves in 4x1, each computes 32x64 (acc[2][4])
// AF32=1: A operand is fp32, staged via vec-load + cvt + ds_write (for attn@V).
// OBF=1: write bf16 C; else fp32. GELU applies exact gelu in epilogue.
// Batched via blockIdx.z = (zb*8 + zh) with element strides per operand.
// ---------------------------------------------------------------------------
template<int BN, int AF32, int GELU, int OBF>
__global__ __launch_bounds__(256) void gemm_m97(
    const void* __restrict__ Ap, const bf16_t* __restrict__ Bp,
    void* __restrict__ Cp, const float* __restrict__ bias,
    int lda, int ldb, int ldc, int K,
    long long sAb, long long sAh, long long sBb, long long sBh,
    long long sCb, long long sCh, float alpha)
{
    constexpr int WR = (BN == 128) ? 2 : 4;   // wave grid rows
    constexpr int WM = 128 / WR;              // rows per wave: 64 or 32
    constexpr int MI = WM / 16;               // 4 or 2 row-fragments

    __shared__ __align__(16) bf16_t As[128 * 64];
    __shared__ __align__(16) bf16_t Bs[BN * 64];

    const int m0 = blockIdx.x * 128, n0 = blockIdx.y * BN;
    const int z = blockIdx.z, zb = z >> 3, zh = z & 7;

    const bf16_t* A  = (const bf16_t*)Ap;
    const float*  Af = (const float*)Ap;
    if (AF32) Af += zb * sAb + zh * sAh + (long long)m0 * lda;
    else      A  += zb * sAb + zh * sAh + (long long)m0 * lda;
    const bf16_t* B = Bp + zb * sBb + zh * sBh + (long long)n0 * ldb;

    const int tid = threadIdx.x, wave = tid >> 6, lane = tid & 63;
    const int q = lane >> 4, r = lane & 15;
    const int wr = wave % WR, wc = wave / WR;

    f32x4 acc[MI][4];
#pragma unroll
    for (int i = 0; i < MI; i++)
#pragma unroll
        for (int j = 0; j < 4; j++) acc[i][j] = (f32x4){0.f, 0.f, 0.f, 0.f};

    for (int k0 = 0; k0 < K; k0 += 64) {
        if (AF32) {
            // A tile 128x64 fp32 -> bf16 LDS (2048 float4, 8 per thread)
#pragma unroll
            for (int it = 0; it < 8; it++) {
                int chunk = it * 256 + tid;
                int row = chunk >> 4, c4 = (chunk & 15) << 2;
                float4 v = *(const float4*)(Af + (long long)row * lda + k0 + c4);
                bf16x4 p;
                p[0] = (bf16_t)v.x; p[1] = (bf16_t)v.y; p[2] = (bf16_t)v.z; p[3] = (bf16_t)v.w;
                *(bf16x4*)(As + row * 64 + c4) = p;
            }
        } else {
            // A tile 128x64 bf16 = 1024 x 16B chunks, 4 per thread
#pragma unroll
            for (int it = 0; it < 4; it++) {
                int chunk = it * 256 + tid;           // row = chunk>>3 (8 chunks/row)
                int row = chunk >> 3, c8 = (chunk & 7) << 3;
                gld16(A + (long long)row * lda + k0 + c8,
                      As + (it * 256 + wave * 64) * 8);   // wave-uniform LDS base
            }
        }
        // B tile BNx64 bf16
#pragma unroll
        for (int it = 0; it < BN / 32; it++) {
            int chunk = it * 256 + tid;
            int row = chunk >> 3, c8 = (chunk & 7) << 3;
            gld16(B + (long long)row * ldb + k0 + c8,
                  Bs + (it * 256 + wave * 64) * 8);
        }
        __syncthreads();   // compiler drains vmcnt+lgkmcnt here
#pragma unroll
        for (int kk = 0; kk < 64; kk += 32) {
            bf16x8 av[MI], bv[4];
#pragma unroll
            for (int mi = 0; mi < MI; mi++)
                av[mi] = *(const bf16x8*)(As + (wr * WM + mi * 16 + r) * 64 + kk + q * 8);
#pragma unroll
            for (int ni = 0; ni < 4; ni++)
                bv[ni] = *(const bf16x8*)(Bs + (wc * 64 + ni * 16 + r) * 64 + kk + q * 8);
#pragma unroll
            for (int mi = 0; mi < MI; mi++)
#pragma unroll
                for (int ni = 0; ni < 4; ni++)
                    acc[mi][ni] = __builtin_amdgcn_mfma_f32_16x16x32_bf16(
                        av[mi], bv[ni], acc[mi][ni], 0, 0, 0);
        }
        __syncthreads();
    }

    // epilogue: C/D frag mapping col = lane&15, row = (lane>>4)*4 + reg
    const long long cb = (long long)zb * sCb + (long long)zh * sCh;
#pragma unroll
    for (int ni = 0; ni < 4; ni++) {
        int col = n0 + wc * 64 + ni * 16 + r;
        float bvl = bias ? bias[col] : 0.f;
#pragma unroll
        for (int mi = 0; mi < MI; mi++) {
#pragma unroll
            for (int i = 0; i < 4; i++) {
                int row = m0 + wr * WM + mi * 16 + q * 4 + i;
                float v = acc[mi][ni][i] * alpha + bvl;
                if (GELU) v = 0.5f * v * (1.f + erff(v * 0.70710678118654752f));
                if (OBF) ((bf16_t*)Cp)[cb + (long long)row * ldc + col] = (bf16_t)v;
                else     ((float*)Cp)[cb + (long long)row * ldc + col] = v;
            }
        }
    }
}

// ---------------------------------------------------------------------------
// Per-(b,h) transpose of V out of bf16 qkv: Vt[z][d][k] = qkv[b*512+k][1024+h*64+d]
// ---------------------------------------------------------------------------
__global__ __launch_bounds__(256) void transpose_v(
    const bf16_t* __restrict__ qkv, bf16_t* __restrict__ Vt)
{
    int z = blockIdx.x, b = z >> 3, h = z & 7;
    int k0 = blockIdx.y * 64;
    __shared__ bf16_t t[64][72];                 // padded rows: no bank conflicts
    const bf16_t* src = qkv + (long long)(b * 512 + k0) * 1536 + 1024 + h * 64;
    int tid = threadIdx.x;
#pragma unroll
    for (int it = 0; it < 2; it++) {
        int idx = tid + 256 * it;                // 512 chunks of 8 bf16
        int i = idx >> 3, j8 = (idx & 7) << 3;
        bf16x8 v = *(const bf16x8*)(src + (long long)i * 1536 + j8);
#pragma unroll
        for (int j = 0; j < 8; j++) t[i][j8 + j] = v[j];
    }
    __syncthreads();
    bf16_t* dst = Vt + (long long)z * 32768 + k0;
#pragma unroll
    for (int it = 0; it < 2; it++) {
        int idx = tid + 256 * it;
        int d = idx >> 3, kx = (idx & 7) << 3;
        bf16x8 v;
#pragma unroll
        for (int j = 0; j < 8; j++) v[j] = t[kx + j][d];
        *(bf16x8*)(dst + (long long)d * 512 + kx) = v;
    }
}

// ---------------------------------------------------------------------------
// In-place masked softmax over rows of 512. One wave per row.
// ---------------------------------------------------------------------------
__global__ __launch_bounds__(256) void softmax_kernel(
    float* __restrict__ a, const int* __restrict__ amask)
{
    long long row = (long long)blockIdx.x * 4 + (threadIdx.x >> 6);
    int lane = threadIdx.x & 63;
    int b = (int)(row >> 12);                    // row = (b*8+h)*512 + q
    float* p = a + row * 512;
    const int* mrow = amask + b * 512;

    float v[8];
    float mx = -3.0e38f;
#pragma unroll
    for (int i = 0; i < 2; i++) {
        float4 t = ((const float4*)p)[lane + 64 * i];
        int k0 = (lane + 64 * i) * 4;
        float tv[4] = {t.x, t.y, t.z, t.w};
#pragma unroll
        for (int c = 0; c < 4; c++) {
            float s = (mrow[k0 + c] == 0) ? -__builtin_inff() : tv[c];
            v[i * 4 + c] = s;
            mx = fmaxf(mx, s);
        }
    }
#pragma unroll
    for (int o = 32; o; o >>= 1) mx = fmaxf(mx, __shfl_xor(mx, o));
    float sum = 0.f;
#pragma unroll
    for (int j = 0; j < 8; j++) { v[j] = __expf(v[j] - mx); sum += v[j]; }
#pragma unroll
    for (int o = 32; o; o >>= 1) sum += __shfl_xor(sum, o);
    float inv = 1.f / sum;
#pragma unroll
    for (int i = 0; i < 2; i++) {
        float4 t;
        t.x = v[i * 4 + 0] * inv; t.y = v[i * 4 + 1] * inv;
        t.z = v[i * 4 + 2] * inv; t.w = v[i * 4 + 3] * inv;
        ((float4*)p)[lane + 64 * i] = t;
    }
}

// ---------------------------------------------------------------------------
// x = LayerNorm(x + rsd) * g + b; also writes bf16 copy of result for GEMMs.
// ---------------------------------------------------------------------------
__global__ __launch_bounds__(256) void add_ln(
    float* __restrict__ x, const float* __restrict__ rsd,
    const float* __restrict__ g, const float* __restrict__ bta,
    bf16_t* __restrict__ xb)
{
    long long row = (long long)blockIdx.x * 4 + (threadIdx.x >> 6);
    int lane = threadIdx.x & 63;
    float4* xr = (float4*)(x + row * 512);
    const float4* rr = (const float4*)(rsd + row * 512);
    float4 s0 = xr[lane], s1 = xr[lane + 64];
    float4 r0 = rr[lane], r1 = rr[lane + 64];
    s0.x += r0.x; s0.y += r0.y; s0.z += r0.z; s0.w += r0.w;
    s1.x += r1.x; s1.y += r1.y; s1.z += r1.z; s1.w += r1.w;
    float sum = s0.x + s0.y + s0.z + s0.w + s1.x + s1.y + s1.z + s1.w;
    float sq  = s0.x*s0.x + s0.y*s0.y + s0.z*s0.z + s0.w*s0.w
              + s1.x*s1.x + s1.y*s1.y + s1.z*s1.z + s1.w*s1.w;
#pragma unroll
    for (int o = 32; o; o >>= 1) { sum += __shfl_xor(sum, o); sq += __shfl_xor(sq, o); }
    float mean = sum * (1.f / 512.f);
    float var  = sq * (1.f / 512.f) - mean * mean;
    float rstd = rsqrtf(var + 1e-5f);
    const float4* g4 = (const float4*)g;
    const float4* b4 = (const float4*)bta;
    float4 gg = g4[lane], bb = b4[lane], o0;
    o0.x = (s0.x - mean) * rstd * gg.x + bb.x;
    o0.y = (s0.y - mean) * rstd * gg.y + bb.y;
    o0.z = (s0.z - mean) * rstd * gg.z + bb.z;
    o0.w = (s0.w - mean) * rstd * gg.w + bb.w;
    xr[lane] = o0;
    bf16x4 h0;
    h0[0] = (bf16_t)o0.x; h0[1] = (bf16_t)o0.y; h0[2] = (bf16_t)o0.z; h0[3] = (bf16_t)o0.w;
    *(bf16x4*)(xb + row * 512 + lane * 4) = h0;
    gg = g4[lane + 64]; bb = b4[lane + 64];
    float4 o1;
    o1.x = (s1.x - mean) * rstd * gg.x + bb.x;
    o1.y = (s1.y - mean) * rstd * gg.y + bb.y;
    o1.z = (s1.z - mean) * rstd * gg.z + bb.z;
    o1.w = (s1.w - mean) * rstd * gg.w + bb.w;
    xr[lane + 64] = o1;
    bf16x4 h1;
    h1[0] = (bf16_t)o1.x; h1[1] = (bf16_t)o1.y; h1[2] = (bf16_t)o1.z; h1[3] = (bf16_t)o1.w;
    *(bf16x4*)(xb + row * 512 + 256 + lane * 4) = h1;
}

// ---------------------------------------------------------------------------
// logits[b][c] = dot(x[b*512], cls_w[c]) + cls_b[c].  64 blocks x 1 wave.
// ---------------------------------------------------------------------------
__global__ void cls_head(const float* __restrict__ x, const float* __restrict__ w,
                         const float* __restrict__ cb, float* __restrict__ out)
{
    int b = blockIdx.x >> 1, c = blockIdx.x & 1;
    int lane = threadIdx.x;
    const float* xr = x + (long long)b * 512 * 512;  // CLS token = b*512
    const float* wr = w + c * 512;
    float s = 0.f;
#pragma unroll
    for (int i = 0; i < 8; i++) s += xr[lane + 64 * i] * wr[lane + 64 * i];
#pragma unroll
    for (int o = 32; o; o >>= 1) s += __shfl_xor(s, o);
    if (lane == 0) out[b * 2 + c] = s + cb[c];
}

// ---------------------------------------------------------------------------
extern "C" void kernel_launch(void* const* d_in, const int* in_sizes, int n_in,
                              void* d_out, int out_size, void* d_ws, size_t ws_size,
                              hipStream_t stream)
{
    const int*   ids   = (const int*)d_in[0];
    const int*   amask = (const int*)d_in[1];
    const float* emb   = (const float*)d_in[2];
    const float* pos   = (const float*)d_in[3];
    const float* in_w  = (const float*)d_in[4];
    const float* in_b  = (const float*)d_in[5];
    const float* out_w = (const float*)d_in[6];
    const float* out_b = (const float*)d_in[7];
    const float* ln1g  = (const float*)d_in[8];
    const float* ln1b  = (const float*)d_in[9];
    const float* ln2g  = (const float*)d_in[10];
    const float* ln2b  = (const float*)d_in[11];
    const float* f1w   = (const float*)d_in[12];
    const float* f1b   = (const float*)d_in[13];
    const float* f2w   = (const float*)d_in[14];
    const float* f2b   = (const float*)d_in[15];
    const float* clsw  = (const float*)d_in[16];
    const float* clsb  = (const float*)d_in[17];

    float* outp = (float*)d_out;
    float* ws = (float*)d_ws;
    // ws layout (float units), total 46,661,632 f = 186.6 MB (<= prior 201 MB use):
    //   x     fp32 [16384,512]            @ 0          (8,388,608)
    //   xb    bf16 [16384,512]            @ 8,388,608  (4,194,304)
    //   pg    fp32 [16384,512]            @ 12,582,912 (8,388,608)   proj / ffn2 out
    //   Ob    bf16 [16384,512]            @ 20,971,520 (4,194,304)   attn@V out
    //   qkvb  bf16 [16384,1536]           @ 25,165,824 (12,582,912)
    //   Vt    bf16 [256,64,512]           @ 37,748,736 (4,194,304)
    //   fb    bf16 [16384,2048] overlays qkvb+Vt (dead by ffn1 time)
    //   wb    bf16 weights                @ 41,943,040 (4,718,592)
    float*  x    = ws;
    bf16_t* xb   = (bf16_t*)(ws + 8388608);
    float*  pg   = ws + 12582912;
    bf16_t* Ob   = (bf16_t*)(ws + 20971520);
    bf16_t* qkvb = (bf16_t*)(ws + 25165824);
    bf16_t* Vt   = (bf16_t*)(ws + 37748736);
    bf16_t* fb   = qkvb;                       // overlay
    bf16_t* wb   = (bf16_t*)(ws + 41943040);
    bf16_t* w_in  = wb;                        // [3,1536,512]
    bf16_t* w_out = wb + 2359296;              // [3,512,512]
    bf16_t* w_f1  = wb + 3145728;              // [3,2048,512]
    bf16_t* w_f2  = wb + 6291456;              // [3,512,2048]

    // weight conversion (~38 MB read, ~10 us)
    cvt_bf16<<<2304, 256, 0, stream>>>(in_w,  w_in);
    cvt_bf16<<< 768, 256, 0, stream>>>(out_w, w_out);
    cvt_bf16<<<3072, 256, 0, stream>>>(f1w,   w_f1);
    cvt_bf16<<<3072, 256, 0, stream>>>(f2w,   w_f2);

    embed_kernel<<<8192, 256, 0, stream>>>(ids, emb, pos, x, xb);

    for (int l = 0; l < 3; l++) {
        float* attnL = outp + 64 + (long long)l * 67108864;  // [32,8,512,512]

        // qkv = x @ Wqkv^T + b  -> bf16 [16384,1536]
        gemm_m97<128, 0, 0, 1><<<dim3(128, 12, 1), 256, 0, stream>>>(
            xb, w_in + (long long)l * 786432, qkvb, in_b + l * 1536,
            512, 512, 1536, 512, 0, 0, 0, 0, 0, 0, 1.f);

        // Vt[b,h][d][k] (bf16)
        transpose_v<<<dim3(256, 8), 256, 0, stream>>>(qkvb, Vt);

        // scores = 0.125 * Q @ K^T per (b,h): [512,512] fp32 (output buffer)
        gemm_m97<128, 0, 0, 0><<<dim3(4, 4, 256), 256, 0, stream>>>(
            qkvb, qkvb + 512, attnL, nullptr,
            1536, 1536, 512, 64,
            786432, 64, 786432, 64, 2097152, 262144, 0.125f);

        // in-place masked softmax (this IS output 1)
        softmax_kernel<<<32768, 256, 0, stream>>>(attnL, amask);

        // o = attn(fp32) @ V -> bf16 [16384,512] token-major (cols h*64+d)
        gemm_m97<64, 1, 0, 1><<<dim3(4, 1, 256), 256, 0, stream>>>(
            attnL, Vt, Ob, nullptr,
            512, 512, 512, 512,
            2097152, 262144, 262144, 32768, 262144, 64, 1.f);

        // proj = o @ Wout^T + b -> fp32
        gemm_m97<128, 0, 0, 0><<<dim3(128, 4, 1), 256, 0, stream>>>(
            Ob, w_out + (long long)l * 262144, pg, out_b + l * 512,
            512, 512, 512, 512, 0, 0, 0, 0, 0, 0, 1.f);

        // x = LN1(x + proj), write xb
        add_ln<<<4096, 256, 0, stream>>>(x, pg, ln1g + l * 512, ln1b + l * 512, xb);

        // f = gelu(x @ W1^T + b1) -> bf16 [16384,2048]
        gemm_m97<128, 0, 1, 1><<<dim3(128, 16, 1), 256, 0, stream>>>(
            xb, w_f1 + (long long)l * 1048576, fb, f1b + l * 2048,
            512, 512, 2048, 512, 0, 0, 0, 0, 0, 0, 1.f);

        // g = f @ W2^T + b2 -> fp32
        gemm_m97<128, 0, 0, 0><<<dim3(128, 4, 1), 256, 0, stream>>>(
            fb, w_f2 + (long long)l * 1048576, pg, f2b + l * 512,
            2048, 2048, 512, 2048, 0, 0, 0, 0, 0, 0, 1.f);

        // x = LN2(x + g), write xb
        add_ln<<<4096, 256, 0, stream>>>(x, pg, ln2g + l * 512, ln2b + l * 512, xb);
    }

    cls_head<<<64, 64, 0, stream>>>(x, clsw, clsb, outp);
}

// Round 2
// 2069.022 us; speedup vs baseline: 1.4353x; 1.0659x over previous
//
#include <hip/hip_runtime.h>
#include <hip/hip_bf16.h>

// ---------------------------------------------------------------------------
// 3-layer BERT-ish encoder forward on MI355X (gfx950).
// m97-structure bf16 MFMA GEMMs + fused scores+masked-softmax attention kernel.
//   - All dense matmuls: 128x128 (or 128x64) tile, BK=64, 4 waves,
//     bf16 staged via __builtin_amdgcn_global_load_lds (16B), fp32 accum.
//   - Attention: one fused kernel per (b,h, 64 q-rows): K staged in LDS,
//     Q@K^T into 128-VGPR full-row accumulator, mask+softmax in registers,
//     single write of the normalized attention weights (output #1).
// Activations flow as bf16 (same rounding points as verified round 1).
// ---------------------------------------------------------------------------

typedef __bf16 bf16_t;
typedef __bf16 bf16x4 __attribute__((ext_vector_type(4)));
typedef __bf16 bf16x8 __attribute__((ext_vector_type(8)));
typedef float  f32x4  __attribute__((ext_vector_type(4)));

__device__ __forceinline__ void gld16(const bf16_t* g, bf16_t* l) {
    // direct global->LDS, 16 bytes/lane; LDS dest is wave-uniform base + lane*16
    __builtin_amdgcn_global_load_lds((const __attribute__((address_space(1))) void*)g,
                                     (__attribute__((address_space(3))) void*)l, 16, 0, 0);
}

// ---------------------------------------------------------------------------
// fp32 -> bf16 bulk convert (weights). One float4 -> bf16x4 per thread.
// ---------------------------------------------------------------------------
__global__ __launch_bounds__(256) void cvt_bf16(
    const float* __restrict__ s, bf16_t* __restrict__ d)
{
    int g = blockIdx.x * 256 + threadIdx.x;
    float4 v = ((const float4*)s)[g];
    bf16x4 p;
    p[0] = (bf16_t)v.x; p[1] = (bf16_t)v.y; p[2] = (bf16_t)v.z; p[3] = (bf16_t)v.w;
    ((bf16x4*)d)[g] = p;
}

// ---------------------------------------------------------------------------
// Embedding: x[t] = emb[ids[t]] + pos_emb[t % 512]; also writes bf16 copy.
// ---------------------------------------------------------------------------
__global__ __launch_bounds__(256) void embed_kernel(
    const int* __restrict__ ids, const float* __restrict__ emb,
    const float* __restrict__ pos, float* __restrict__ x, bf16_t* __restrict__ xb)
{
    int g = blockIdx.x * 256 + threadIdx.x;        // float4 units
    int token = g >> 7, c4 = g & 127;
    int id = ids[token];
    float4 e = ((const float4*)emb)[(long long)id * 128 + c4];
    float4 p = ((const float4*)pos)[(long long)(token & 511) * 128 + c4];
    e.x += p.x; e.y += p.y; e.z += p.z; e.w += p.w;
    ((float4*)x)[g] = e;
    bf16x4 h;
    h[0] = (bf16_t)e.x; h[1] = (bf16_t)e.y; h[2] = (bf16_t)e.z; h[3] = (bf16_t)e.w;
    ((bf16x4*)xb)[g] = h;
}

// ---------------------------------------------------------------------------
// m97-style GEMM: C = alpha * A (MxK) * B^T (B is [N,K] bf16) + bias.
// BM=128 fixed, BN in {128,64}. BK=64. 256 threads = 4 waves.
// AF32=1: A operand is fp32, staged via vec-load + cvt + ds_write (attn@V).
// OBF=1: write bf16 C; else fp32. GELU applies exact gelu in epilogue.
// ---------------------------------------------------------------------------
template<int BN, int AF32, int GELU, int OBF>
__global__ __launch_bounds__(256) void gemm_m97(
    const void* __restrict__ Ap, const bf16_t* __restrict__ Bp,
    void* __restrict__ Cp, const float* __restrict__ bias,
    int lda, int ldb, int ldc, int K,
    long long sAb, long long sAh, long long sBb, long long sBh,
    long long sCb, long long sCh, float alpha)
{
    constexpr int WR = (BN == 128) ? 2 : 4;   // wave grid rows
    constexpr int WM = 128 / WR;              // rows per wave: 64 or 32
    constexpr int MI = WM / 16;               // 4 or 2 row-fragments

    __shared__ __align__(16) bf16_t As[128 * 64];
    __shared__ __align__(16) bf16_t Bs[BN * 64];

    const int m0 = blockIdx.x * 128, n0 = blockIdx.y * BN;
    const int z = blockIdx.z, zb = z >> 3, zh = z & 7;

    const bf16_t* A  = (const bf16_t*)Ap;
    const float*  Af = (const float*)Ap;
    if (AF32) Af += zb * sAb + zh * sAh + (long long)m0 * lda;
    else      A  += zb * sAb + zh * sAh + (long long)m0 * lda;
    const bf16_t* B = Bp + zb * sBb + zh * sBh + (long long)n0 * ldb;

    const int tid = threadIdx.x, wave = tid >> 6, lane = tid & 63;
    const int q = lane >> 4, r = lane & 15;
    const int wr = wave % WR, wc = wave / WR;

    f32x4 acc[MI][4];
#pragma unroll
    for (int i = 0; i < MI; i++)
#pragma unroll
        for (int j = 0; j < 4; j++) acc[i][j] = (f32x4){0.f, 0.f, 0.f, 0.f};

    for (int k0 = 0; k0 < K; k0 += 64) {
        if (AF32) {
            // A tile 128x64 fp32 -> bf16 LDS (2048 float4, 8 per thread)
#pragma unroll
            for (int it = 0; it < 8; it++) {
                int chunk = it * 256 + tid;
                int row = chunk >> 4, c4 = (chunk & 15) << 2;
                float4 v = *(const float4*)(Af + (long long)row * lda + k0 + c4);
                bf16x4 p;
                p[0] = (bf16_t)v.x; p[1] = (bf16_t)v.y; p[2] = (bf16_t)v.z; p[3] = (bf16_t)v.w;
                *(bf16x4*)(As + row * 64 + c4) = p;
            }
        } else {
            // A tile 128x64 bf16 = 1024 x 16B chunks, 4 per thread
#pragma unroll
            for (int it = 0; it < 4; it++) {
                int chunk = it * 256 + tid;           // row = chunk>>3 (8 chunks/row)
                int row = chunk >> 3, c8 = (chunk & 7) << 3;
                gld16(A + (long long)row * lda + k0 + c8,
                      As + (it * 256 + wave * 64) * 8);   // wave-uniform LDS base
            }
        }
        // B tile BNx64 bf16
#pragma unroll
        for (int it = 0; it < BN / 32; it++) {
            int chunk = it * 256 + tid;
            int row = chunk >> 3, c8 = (chunk & 7) << 3;
            gld16(B + (long long)row * ldb + k0 + c8,
                  Bs + (it * 256 + wave * 64) * 8);
        }
        __syncthreads();   // compiler drains vmcnt+lgkmcnt here
#pragma unroll
        for (int kk = 0; kk < 64; kk += 32) {
            bf16x8 av[MI], bv[4];
#pragma unroll
            for (int mi = 0; mi < MI; mi++)
                av[mi] = *(const bf16x8*)(As + (wr * WM + mi * 16 + r) * 64 + kk + q * 8);
#pragma unroll
            for (int ni = 0; ni < 4; ni++)
                bv[ni] = *(const bf16x8*)(Bs + (wc * 64 + ni * 16 + r) * 64 + kk + q * 8);
#pragma unroll
            for (int mi = 0; mi < MI; mi++)
#pragma unroll
                for (int ni = 0; ni < 4; ni++)
                    acc[mi][ni] = __builtin_amdgcn_mfma_f32_16x16x32_bf16(
                        av[mi], bv[ni], acc[mi][ni], 0, 0, 0);
        }
        __syncthreads();
    }

    // epilogue: C/D frag mapping col = lane&15, row = (lane>>4)*4 + reg
    const long long cb = (long long)zb * sCb + (long long)zh * sCh;
#pragma unroll
    for (int ni = 0; ni < 4; ni++) {
        int col = n0 + wc * 64 + ni * 16 + r;
        float bvl = bias ? bias[col] : 0.f;
#pragma unroll
        for (int mi = 0; mi < MI; mi++) {
#pragma unroll
            for (int i = 0; i < 4; i++) {
                int row = m0 + wr * WM + mi * 16 + q * 4 + i;
                float v = acc[mi][ni][i] * alpha + bvl;
                if (GELU) v = 0.5f * v * (1.f + erff(v * 0.70710678118654752f));
                if (OBF) ((bf16_t*)Cp)[cb + (long long)row * ldc + col] = (bf16_t)v;
                else     ((float*)Cp)[cb + (long long)row * ldc + col] = v;
            }
        }
    }
}

// ---------------------------------------------------------------------------
// Fused attention scores + masked softmax.
// Block = one (b,h) x 64 q-rows. 4 waves; wave w owns q-rows [w*16, w*16+16).
// K (512x64 bf16, 64KB) staged to LDS via global_load_lds; Q frags from
// global; 64 MFMA/wave accumulate the FULL 512-key row (acc[32] = 128 VGPR).
// Softmax in registers: per-lane over 32 frags + shfl_xor over 16-lane group.
// Single fp32 write of normalized attention weights (this IS output #1).
// ---------------------------------------------------------------------------
__global__ __launch_bounds__(256) void attn_scores_softmax(
    const bf16_t* __restrict__ qkv, const int* __restrict__ amask,
    float* __restrict__ attn)
{
    __shared__ __align__(16) bf16_t Ks[512 * 64];   // [key][d], linear
    __shared__ float bias_s[512];

    const int z = blockIdx.y, b = z >> 3, h = z & 7;
    const int q0 = blockIdx.x * 64;
    const int tid = threadIdx.x, wave = tid >> 6, lane = tid & 63;
    const int q = lane >> 4, r = lane & 15;

    // stage K tile: rows = keys 0..511, cols = d 0..63
    const bf16_t* Kg = qkv + (long long)(b * 512) * 1536 + 512 + h * 64;
#pragma unroll
    for (int it = 0; it < 16; it++) {
        int chunk = it * 256 + tid;                 // 8 chunks (of 8 bf16) per row
        int row = chunk >> 3, c8 = (chunk & 7) << 3;
        gld16(Kg + (long long)row * 1536 + c8, Ks + (it * 256 + wave * 64) * 8);
    }
    // mask -> additive bias
    {
        int i0 = tid * 2;
        bias_s[i0]     = (amask[b * 512 + i0]     == 0) ? -__builtin_inff() : 0.f;
        bias_s[i0 + 1] = (amask[b * 512 + i0 + 1] == 0) ? -__builtin_inff() : 0.f;
    }
    // Q fragments: A-frag layout [m = lane&15][k = (lane>>4)*8 + j]
    const bf16_t* Qg = qkv + (long long)(b * 512 + q0 + wave * 16 + r) * 1536 + h * 64;
    bf16x8 av0 = *(const bf16x8*)(Qg + q * 8);
    bf16x8 av1 = *(const bf16x8*)(Qg + 32 + q * 8);
    __syncthreads();

    f32x4 acc[32];
#pragma unroll
    for (int nf = 0; nf < 32; nf++) acc[nf] = (f32x4){0.f, 0.f, 0.f, 0.f};

#pragma unroll
    for (int nf = 0; nf < 32; nf++) {
        bf16x8 b0 = *(const bf16x8*)(Ks + (nf * 16 + r) * 64 + q * 8);
        bf16x8 b1 = *(const bf16x8*)(Ks + (nf * 16 + r) * 64 + 32 + q * 8);
        acc[nf] = __builtin_amdgcn_mfma_f32_16x16x32_bf16(av0, b0, acc[nf], 0, 0, 0);
        acc[nf] = __builtin_amdgcn_mfma_f32_16x16x32_bf16(av1, b1, acc[nf], 0, 0, 0);
    }

    // scale + mask + row max  (C frag: col(key) = nf*16 + r, row = q*4 + i)
    float mx[4] = {-3.0e38f, -3.0e38f, -3.0e38f, -3.0e38f};
#pragma unroll
    for (int nf = 0; nf < 32; nf++) {
        float bl = bias_s[nf * 16 + r];
#pragma unroll
        for (int i = 0; i < 4; i++) {
            float s = acc[nf][i] * 0.125f + bl;
            acc[nf][i] = s;
            mx[i] = fmaxf(mx[i], s);
        }
    }
#pragma unroll
    for (int off = 8; off; off >>= 1)
#pragma unroll
        for (int i = 0; i < 4; i++) mx[i] = fmaxf(mx[i], __shfl_xor(mx[i], off));

    float sm[4] = {0.f, 0.f, 0.f, 0.f};
#pragma unroll
    for (int nf = 0; nf < 32; nf++)
#pragma unroll
        for (int i = 0; i < 4; i++) {
            float e = __expf(acc[nf][i] - mx[i]);
            acc[nf][i] = e;
            sm[i] += e;
        }
#pragma unroll
    for (int off = 8; off; off >>= 1)
#pragma unroll
        for (int i = 0; i < 4; i++) sm[i] += __shfl_xor(sm[i], off);

    float inv[4];
#pragma unroll
    for (int i = 0; i < 4; i++) inv[i] = 1.f / sm[i];

    float* out = attn + (long long)z * 262144 + (long long)(q0 + wave * 16) * 512;
#pragma unroll
    for (int nf = 0; nf < 32; nf++)
#pragma unroll
        for (int i = 0; i < 4; i++)
            out[(q * 4 + i) * 512 + nf * 16 + r] = acc[nf][i] * inv[i];
}

// ---------------------------------------------------------------------------
// Per-(b,h) transpose of V out of bf16 qkv: Vt[z][d][k] = qkv[b*512+k][1024+h*64+d]
// ---------------------------------------------------------------------------
__global__ __launch_bounds__(256) void transpose_v(
    const bf16_t* __restrict__ qkv, bf16_t* __restrict__ Vt)
{
    int z = blockIdx.x, b = z >> 3, h = z & 7;
    int k0 = blockIdx.y * 64;
    __shared__ bf16_t t[64][72];                 // padded rows: no bank conflicts
    const bf16_t* src = qkv + (long long)(b * 512 + k0) * 1536 + 1024 + h * 64;
    int tid = threadIdx.x;
#pragma unroll
    for (int it = 0; it < 2; it++) {
        int idx = tid + 256 * it;                // 512 chunks of 8 bf16
        int i = idx >> 3, j8 = (idx & 7) << 3;
        bf16x8 v = *(const bf16x8*)(src + (long long)i * 1536 + j8);
#pragma unroll
        for (int j = 0; j < 8; j++) t[i][j8 + j] = v[j];
    }
    __syncthreads();
    bf16_t* dst = Vt + (long long)z * 32768 + k0;
#pragma unroll
    for (int it = 0; it < 2; it++) {
        int idx = tid + 256 * it;
        int d = idx >> 3, kx = (idx & 7) << 3;
        bf16x8 v;
#pragma unroll
        for (int j = 0; j < 8; j++) v[j] = t[kx + j][d];
        *(bf16x8*)(dst + (long long)d * 512 + kx) = v;
    }
}

// ---------------------------------------------------------------------------
// x = LayerNorm(x + rsd) * g + b; also writes bf16 copy of result for GEMMs.
// ---------------------------------------------------------------------------
__global__ __launch_bounds__(256) void add_ln(
    float* __restrict__ x, const float* __restrict__ rsd,
    const float* __restrict__ g, const float* __restrict__ bta,
    bf16_t* __restrict__ xb)
{
    long long row = (long long)blockIdx.x * 4 + (threadIdx.x >> 6);
    int lane = threadIdx.x & 63;
    float4* xr = (float4*)(x + row * 512);
    const float4* rr = (const float4*)(rsd + row * 512);
    float4 s0 = xr[lane], s1 = xr[lane + 64];
    float4 r0 = rr[lane], r1 = rr[lane + 64];
    s0.x += r0.x; s0.y += r0.y; s0.z += r0.z; s0.w += r0.w;
    s1.x += r1.x; s1.y += r1.y; s1.z += r1.z; s1.w += r1.w;
    float sum = s0.x + s0.y + s0.z + s0.w + s1.x + s1.y + s1.z + s1.w;
    float sq  = s0.x*s0.x + s0.y*s0.y + s0.z*s0.z + s0.w*s0.w
              + s1.x*s1.x + s1.y*s1.y + s1.z*s1.z + s1.w*s1.w;
#pragma unroll
    for (int o = 32; o; o >>= 1) { sum += __shfl_xor(sum, o); sq += __shfl_xor(sq, o); }
    float mean = sum * (1.f / 512.f);
    float var  = sq * (1.f / 512.f) - mean * mean;
    float rstd = rsqrtf(var + 1e-5f);
    const float4* g4 = (const float4*)g;
    const float4* b4 = (const float4*)bta;
    float4 gg = g4[lane], bb = b4[lane], o0;
    o0.x = (s0.x - mean) * rstd * gg.x + bb.x;
    o0.y = (s0.y - mean) * rstd * gg.y + bb.y;
    o0.z = (s0.z - mean) * rstd * gg.z + bb.z;
    o0.w = (s0.w - mean) * rstd * gg.w + bb.w;
    xr[lane] = o0;
    bf16x4 h0;
    h0[0] = (bf16_t)o0.x; h0[1] = (bf16_t)o0.y; h0[2] = (bf16_t)o0.z; h0[3] = (bf16_t)o0.w;
    *(bf16x4*)(xb + row * 512 + lane * 4) = h0;
    gg = g4[lane + 64]; bb = b4[lane + 64];
    float4 o1;
    o1.x = (s1.x - mean) * rstd * gg.x + bb.x;
    o1.y = (s1.y - mean) * rstd * gg.y + bb.y;
    o1.z = (s1.z - mean) * rstd * gg.z + bb.z;
    o1.w = (s1.w - mean) * rstd * gg.w + bb.w;
    xr[lane + 64] = o1;
    bf16x4 h1;
    h1[0] = (bf16_t)o1.x; h1[1] = (bf16_t)o1.y; h1[2] = (bf16_t)o1.z; h1[3] = (bf16_t)o1.w;
    *(bf16x4*)(xb + row * 512 + 256 + lane * 4) = h1;
}

// ---------------------------------------------------------------------------
// logits[b][c] = dot(x[b*512], cls_w[c]) + cls_b[c].  64 blocks x 1 wave.
// ---------------------------------------------------------------------------
__global__ void cls_head(const float* __restrict__ x, const float* __restrict__ w,
                         const float* __restrict__ cb, float* __restrict__ out)
{
    int b = blockIdx.x >> 1, c = blockIdx.x & 1;
    int lane = threadIdx.x;
    const float* xr = x + (long long)b * 512 * 512;  // CLS token = b*512
    const float* wr = w + c * 512;
    float s = 0.f;
#pragma unroll
    for (int i = 0; i < 8; i++) s += xr[lane + 64 * i] * wr[lane + 64 * i];
#pragma unroll
    for (int o = 32; o; o >>= 1) s += __shfl_xor(s, o);
    if (lane == 0) out[b * 2 + c] = s + cb[c];
}

// ---------------------------------------------------------------------------
extern "C" void kernel_launch(void* const* d_in, const int* in_sizes, int n_in,
                              void* d_out, int out_size, void* d_ws, size_t ws_size,
                              hipStream_t stream)
{
    const int*   ids   = (const int*)d_in[0];
    const int*   amask = (const int*)d_in[1];
    const float* emb   = (const float*)d_in[2];
    const float* pos   = (const float*)d_in[3];
    const float* in_w  = (const float*)d_in[4];
    const float* in_b  = (const float*)d_in[5];
    const float* out_w = (const float*)d_in[6];
    const float* out_b = (const float*)d_in[7];
    const float* ln1g  = (const float*)d_in[8];
    const float* ln1b  = (const float*)d_in[9];
    const float* ln2g  = (const float*)d_in[10];
    const float* ln2b  = (const float*)d_in[11];
    const float* f1w   = (const float*)d_in[12];
    const float* f1b   = (const float*)d_in[13];
    const float* f2w   = (const float*)d_in[14];
    const float* f2b   = (const float*)d_in[15];
    const float* clsw  = (const float*)d_in[16];
    const float* clsb  = (const float*)d_in[17];

    float* outp = (float*)d_out;
    float* ws = (float*)d_ws;
    // ws layout (float units):
    //   x     fp32 [16384,512]            @ 0          (8,388,608)
    //   xb    bf16 [16384,512]            @ 8,388,608  (4,194,304)
    //   pg    fp32 [16384,512]            @ 12,582,912 (8,388,608)   proj / ffn2 out
    //   Ob    bf16 [16384,512]            @ 20,971,520 (4,194,304)   attn@V out
    //   qkvb  bf16 [16384,1536]           @ 25,165,824 (12,582,912)
    //   Vt    bf16 [256,64,512]           @ 37,748,736 (4,194,304)
    //   fb    bf16 [16384,2048] overlays qkvb+Vt (dead by ffn1 time)
    //   wb    bf16 weights                @ 41,943,040 (4,718,592)
    float*  x    = ws;
    bf16_t* xb   = (bf16_t*)(ws + 8388608);
    float*  pg   = ws + 12582912;
    bf16_t* Ob   = (bf16_t*)(ws + 20971520);
    bf16_t* qkvb = (bf16_t*)(ws + 25165824);
    bf16_t* Vt   = (bf16_t*)(ws + 37748736);
    bf16_t* fb   = qkvb;                       // overlay
    bf16_t* wb   = (bf16_t*)(ws + 41943040);
    bf16_t* w_in  = wb;                        // [3,1536,512]
    bf16_t* w_out = wb + 2359296;              // [3,512,512]
    bf16_t* w_f1  = wb + 3145728;              // [3,2048,512]
    bf16_t* w_f2  = wb + 6291456;              // [3,512,2048]

    // weight conversion (~38 MB read, ~10 us)
    cvt_bf16<<<2304, 256, 0, stream>>>(in_w,  w_in);
    cvt_bf16<<< 768, 256, 0, stream>>>(out_w, w_out);
    cvt_bf16<<<3072, 256, 0, stream>>>(f1w,   w_f1);
    cvt_bf16<<<3072, 256, 0, stream>>>(f2w,   w_f2);

    embed_kernel<<<8192, 256, 0, stream>>>(ids, emb, pos, x, xb);

    for (int l = 0; l < 3; l++) {
        float* attnL = outp + 64 + (long long)l * 67108864;  // [32,8,512,512]

        // qkv = x @ Wqkv^T + b  -> bf16 [16384,1536]
        gemm_m97<128, 0, 0, 1><<<dim3(128, 12, 1), 256, 0, stream>>>(
            xb, w_in + (long long)l * 786432, qkvb, in_b + l * 1536,
            512, 512, 1536, 512, 0, 0, 0, 0, 0, 0, 1.f);

        // Vt[b,h][d][k] (bf16)
        transpose_v<<<dim3(256, 8), 256, 0, stream>>>(qkvb, Vt);

        // attn = softmax(0.125 * Q@K^T + mask) -> fp32 output, one fused pass
        attn_scores_softmax<<<dim3(8, 256), 256, 0, stream>>>(qkvb, amask, attnL);

        // o = attn(fp32) @ V -> bf16 [16384,512] token-major (cols h*64+d)
        gemm_m97<64, 1, 0, 1><<<dim3(4, 1, 256), 256, 0, stream>>>(
            attnL, Vt, Ob, nullptr,
            512, 512, 512, 512,
            2097152, 262144, 262144, 32768, 262144, 64, 1.f);

        // proj = o @ Wout^T + b -> fp32
        gemm_m97<128, 0, 0, 0><<<dim3(128, 4, 1), 256, 0, stream>>>(
            Ob, w_out + (long long)l * 262144, pg, out_b + l * 512,
            512, 512, 512, 512, 0, 0, 0, 0, 0, 0, 1.f);

        // x = LN1(x + proj), write xb
        add_ln<<<4096, 256, 0, stream>>>(x, pg, ln1g + l * 512, ln1b + l * 512, xb);

        // f = gelu(x @ W1^T + b1) -> bf16 [16384,2048]
        gemm_m97<128, 0, 1, 1><<<dim3(128, 16, 1), 256, 0, stream>>>(
            xb, w_f1 + (long long)l * 1048576, fb, f1b + l * 2048,
            512, 512, 2048, 512, 0, 0, 0, 0, 0, 0, 1.f);

        // g = f @ W2^T + b2 -> fp32
        gemm_m97<128, 0, 0, 0><<<dim3(128, 4, 1), 256, 0, stream>>>(
            fb, w_f2 + (long long)l * 1048576, pg, f2b + l * 512,
            2048, 2048, 512, 2048, 0, 0, 0, 0, 0, 0, 1.f);

        // x = LN2(x + g), write xb
        add_ln<<<4096, 256, 0, stream>>>(x, pg, ln2g + l * 512, ln2b + l * 512, xb);
    }

    cls_head<<<64, 64, 0, stream>>>(x, clsw, clsb, outp);
}

// Round 3
// 1991.202 us; speedup vs baseline: 1.4914x; 1.0391x over previous
//
#include <hip/hip_runtime.h>
#include <hip/hip_bf16.h>

// ---------------------------------------------------------------------------
// 3-layer BERT-ish encoder forward on MI355X (gfx950).
// m97-structure bf16 MFMA GEMMs + fully fused attention kernel:
//   scores = Q@K^T -> masked softmax (in registers) -> write P (output #1)
//   -> scatter bf16 P into dead K-LDS -> P@V MFMA -> write O tile (bf16).
// Per (b,h,64 q-rows) block: K (64KB) + Vt (64KB) staged via global_load_lds.
// The 256MB/layer fp32 re-read of P by a separate PV GEMM is eliminated.
// Activations flow as bf16 (same rounding points as verified rounds 1-2).
// ---------------------------------------------------------------------------

typedef __bf16 bf16_t;
typedef __bf16 bf16x4 __attribute__((ext_vector_type(4)));
typedef __bf16 bf16x8 __attribute__((ext_vector_type(8)));
typedef float  f32x4  __attribute__((ext_vector_type(4)));

__device__ __forceinline__ void gld16(const bf16_t* g, bf16_t* l) {
    // direct global->LDS, 16 bytes/lane; LDS dest is wave-uniform base + lane*16
    __builtin_amdgcn_global_load_lds((const __attribute__((address_space(1))) void*)g,
                                     (__attribute__((address_space(3))) void*)l, 16, 0, 0);
}

// ---------------------------------------------------------------------------
// fp32 -> bf16 bulk convert (weights). One float4 -> bf16x4 per thread.
// ---------------------------------------------------------------------------
__global__ __launch_bounds__(256) void cvt_bf16(
    const float* __restrict__ s, bf16_t* __restrict__ d)
{
    int g = blockIdx.x * 256 + threadIdx.x;
    float4 v = ((const float4*)s)[g];
    bf16x4 p;
    p[0] = (bf16_t)v.x; p[1] = (bf16_t)v.y; p[2] = (bf16_t)v.z; p[3] = (bf16_t)v.w;
    ((bf16x4*)d)[g] = p;
}

// ---------------------------------------------------------------------------
// Embedding: x[t] = emb[ids[t]] + pos_emb[t % 512]; also writes bf16 copy.
// ---------------------------------------------------------------------------
__global__ __launch_bounds__(256) void embed_kernel(
    const int* __restrict__ ids, const float* __restrict__ emb,
    const float* __restrict__ pos, float* __restrict__ x, bf16_t* __restrict__ xb)
{
    int g = blockIdx.x * 256 + threadIdx.x;        // float4 units
    int token = g >> 7, c4 = g & 127;
    int id = ids[token];
    float4 e = ((const float4*)emb)[(long long)id * 128 + c4];
    float4 p = ((const float4*)pos)[(long long)(token & 511) * 128 + c4];
    e.x += p.x; e.y += p.y; e.z += p.z; e.w += p.w;
    ((float4*)x)[g] = e;
    bf16x4 h;
    h[0] = (bf16_t)e.x; h[1] = (bf16_t)e.y; h[2] = (bf16_t)e.z; h[3] = (bf16_t)e.w;
    ((bf16x4*)xb)[g] = h;
}

// ---------------------------------------------------------------------------
// m97-style GEMM: C = alpha * A (MxK, bf16) * B^T (B is [N,K] bf16) + bias.
// BM=128, BN=128. BK=64. 256 threads = 4 waves (2x2), 64x64 per wave.
// OBF=1: write bf16 C; else fp32. GELU applies exact gelu in epilogue.
// ---------------------------------------------------------------------------
template<int GELU, int OBF>
__global__ __launch_bounds__(256) void gemm_m97(
    const bf16_t* __restrict__ A, const bf16_t* __restrict__ B,
    void* __restrict__ Cp, const float* __restrict__ bias,
    int lda, int ldb, int ldc, int K, float alpha)
{
    __shared__ __align__(16) bf16_t As[128 * 64];
    __shared__ __align__(16) bf16_t Bs[128 * 64];

    const int m0 = blockIdx.x * 128, n0 = blockIdx.y * 128;
    A += (long long)m0 * lda;
    B += (long long)n0 * ldb;

    const int tid = threadIdx.x, wave = tid >> 6, lane = tid & 63;
    const int q = lane >> 4, r = lane & 15;
    const int wr = wave & 1, wc = wave >> 1;

    f32x4 acc[4][4];
#pragma unroll
    for (int i = 0; i < 4; i++)
#pragma unroll
        for (int j = 0; j < 4; j++) acc[i][j] = (f32x4){0.f, 0.f, 0.f, 0.f};

    for (int k0 = 0; k0 < K; k0 += 64) {
#pragma unroll
        for (int it = 0; it < 4; it++) {
            int chunk = it * 256 + tid;               // 8 chunks (8 bf16) per row
            int row = chunk >> 3, c8 = (chunk & 7) << 3;
            gld16(A + (long long)row * lda + k0 + c8, As + (it * 256 + wave * 64) * 8);
            gld16(B + (long long)row * ldb + k0 + c8, Bs + (it * 256 + wave * 64) * 8);
        }
        __syncthreads();   // compiler drains vmcnt+lgkmcnt here
#pragma unroll
        for (int kk = 0; kk < 64; kk += 32) {
            bf16x8 av[4], bv[4];
#pragma unroll
            for (int mi = 0; mi < 4; mi++)
                av[mi] = *(const bf16x8*)(As + (wr * 64 + mi * 16 + r) * 64 + kk + q * 8);
#pragma unroll
            for (int ni = 0; ni < 4; ni++)
                bv[ni] = *(const bf16x8*)(Bs + (wc * 64 + ni * 16 + r) * 64 + kk + q * 8);
#pragma unroll
            for (int mi = 0; mi < 4; mi++)
#pragma unroll
                for (int ni = 0; ni < 4; ni++)
                    acc[mi][ni] = __builtin_amdgcn_mfma_f32_16x16x32_bf16(
                        av[mi], bv[ni], acc[mi][ni], 0, 0, 0);
        }
        __syncthreads();
    }

    // epilogue: C/D frag mapping col = lane&15, row = (lane>>4)*4 + reg
#pragma unroll
    for (int ni = 0; ni < 4; ni++) {
        int col = n0 + wc * 64 + ni * 16 + r;
        float bvl = bias ? bias[col] : 0.f;
#pragma unroll
        for (int mi = 0; mi < 4; mi++) {
#pragma unroll
            for (int i = 0; i < 4; i++) {
                int row = m0 + wr * 64 + mi * 16 + q * 4 + i;
                float v = acc[mi][ni][i] * alpha + bvl;
                if (GELU) v = 0.5f * v * (1.f + erff(v * 0.70710678118654752f));
                if (OBF) ((bf16_t*)Cp)[(long long)row * ldc + col] = (bf16_t)v;
                else     ((float*)Cp)[(long long)row * ldc + col] = v;
            }
        }
    }
}

// ---------------------------------------------------------------------------
// Fully fused attention: scores + masked softmax + P write + P@V + O write.
// Block = one (b,h) x 64 q-rows. 4 waves; wave w owns q-rows [w*16, w*16+16).
// LDS: Ks[512x64] (K tile, later reused as P[64x512]) + Vs[64x512] (Vt tile).
// ---------------------------------------------------------------------------
__global__ __launch_bounds__(256) void attn_fused(
    const bf16_t* __restrict__ qkv, const bf16_t* __restrict__ Vt,
    const int* __restrict__ amask, float* __restrict__ attn,
    bf16_t* __restrict__ Ob)
{
    __shared__ __align__(16) bf16_t Ks[512 * 64];   // 64KB: K, then P[64][512]
    __shared__ __align__(16) bf16_t Vs[64 * 512];   // 64KB: Vt tile [d][k]
    __shared__ float bias_s[512];

    const int z = blockIdx.y, b = z >> 3, h = z & 7;
    const int q0 = blockIdx.x * 64;
    const int tid = threadIdx.x, wave = tid >> 6, lane = tid & 63;
    const int q = lane >> 4, r = lane & 15;

    // stage K tile [key 0..511][d 0..63]
    const bf16_t* Kg = qkv + (long long)(b * 512) * 1536 + 512 + h * 64;
#pragma unroll
    for (int it = 0; it < 16; it++) {
        int chunk = it * 256 + tid;                 // 8 chunks (of 8 bf16) per row
        int row = chunk >> 3, c8 = (chunk & 7) << 3;
        gld16(Kg + (long long)row * 1536 + c8, Ks + (it * 256 + wave * 64) * 8);
    }
    // stage Vt tile [d 0..63][k 0..511]
    const bf16_t* Vg = Vt + (long long)z * 32768;
#pragma unroll
    for (int it = 0; it < 16; it++) {
        int chunk = it * 256 + tid;                 // 64 chunks per row
        int row = chunk >> 6, c8 = (chunk & 63) << 3;
        gld16(Vg + (long long)row * 512 + c8, Vs + (it * 256 + wave * 64) * 8);
    }
    // mask -> additive bias
    {
        int i0 = tid * 2;
        bias_s[i0]     = (amask[b * 512 + i0]     == 0) ? -__builtin_inff() : 0.f;
        bias_s[i0 + 1] = (amask[b * 512 + i0 + 1] == 0) ? -__builtin_inff() : 0.f;
    }
    // Q fragments: A-frag layout [m = lane&15][k = (lane>>4)*8 + j]
    const bf16_t* Qg = qkv + (long long)(b * 512 + q0 + wave * 16 + r) * 1536 + h * 64;
    bf16x8 av0 = *(const bf16x8*)(Qg + q * 8);
    bf16x8 av1 = *(const bf16x8*)(Qg + 32 + q * 8);
    __syncthreads();

    // QK^T: full 512-key row per wave (C frag: col(key)=nf*16+r, row=q*4+i)
    f32x4 acc[32];
#pragma unroll
    for (int nf = 0; nf < 32; nf++) acc[nf] = (f32x4){0.f, 0.f, 0.f, 0.f};
#pragma unroll
    for (int nf = 0; nf < 32; nf++) {
        bf16x8 b0 = *(const bf16x8*)(Ks + (nf * 16 + r) * 64 + q * 8);
        bf16x8 b1 = *(const bf16x8*)(Ks + (nf * 16 + r) * 64 + 32 + q * 8);
        acc[nf] = __builtin_amdgcn_mfma_f32_16x16x32_bf16(av0, b0, acc[nf], 0, 0, 0);
        acc[nf] = __builtin_amdgcn_mfma_f32_16x16x32_bf16(av1, b1, acc[nf], 0, 0, 0);
    }

    // scale + mask + row max
    float mx[4] = {-3.0e38f, -3.0e38f, -3.0e38f, -3.0e38f};
#pragma unroll
    for (int nf = 0; nf < 32; nf++) {
        float bl = bias_s[nf * 16 + r];
#pragma unroll
        for (int i = 0; i < 4; i++) {
            float s = acc[nf][i] * 0.125f + bl;
            acc[nf][i] = s;
            mx[i] = fmaxf(mx[i], s);
        }
    }
#pragma unroll
    for (int off = 8; off; off >>= 1)
#pragma unroll
        for (int i = 0; i < 4; i++) mx[i] = fmaxf(mx[i], __shfl_xor(mx[i], off));

    float sm[4] = {0.f, 0.f, 0.f, 0.f};
#pragma unroll
    for (int nf = 0; nf < 32; nf++)
#pragma unroll
        for (int i = 0; i < 4; i++) {
            float e = __expf(acc[nf][i] - mx[i]);
            acc[nf][i] = e;
            sm[i] += e;
        }
#pragma unroll
    for (int off = 8; off; off >>= 1)
#pragma unroll
        for (int i = 0; i < 4; i++) sm[i] += __shfl_xor(sm[i], off);
    float inv[4];
#pragma unroll
    for (int i = 0; i < 4; i++) inv[i] = 1.f / sm[i];

    __syncthreads();   // all waves done reading Ks -> safe to overwrite with P

    // write P (fp32, output #1) + scatter bf16 P into P_lds = Ks as [64][512]
    bf16_t* P = Ks;
    float* out = attn + (long long)z * 262144 + (long long)(q0 + wave * 16) * 512;
#pragma unroll
    for (int nf = 0; nf < 32; nf++) {
#pragma unroll
        for (int i = 0; i < 4; i++) {
            float pv = acc[nf][i] * inv[i];
            int rr = q * 4 + i, cc = nf * 16 + r;
            out[(long long)rr * 512 + cc] = pv;
            P[(wave * 16 + rr) * 512 + cc] = (bf16_t)pv;
        }
    }
    __syncthreads();

    // P@V: per wave 16x64 output; A = P rows (m=r), B = Vs rows (n=d)
    f32x4 oacc[4];
#pragma unroll
    for (int ni = 0; ni < 4; ni++) oacc[ni] = (f32x4){0.f, 0.f, 0.f, 0.f};
#pragma unroll
    for (int ks = 0; ks < 16; ks++) {
        bf16x8 pa = *(const bf16x8*)(P + (wave * 16 + r) * 512 + ks * 32 + q * 8);
#pragma unroll
        for (int ni = 0; ni < 4; ni++) {
            bf16x8 vb = *(const bf16x8*)(Vs + (ni * 16 + r) * 512 + ks * 32 + q * 8);
            oacc[ni] = __builtin_amdgcn_mfma_f32_16x16x32_bf16(pa, vb, oacc[ni], 0, 0, 0);
        }
    }

    // O write: token = b*512 + q0 + wave*16 + q*4+i, col = h*64 + ni*16 + r
    bf16_t* ob = Ob + (long long)(b * 512 + q0 + wave * 16) * 512 + h * 64;
#pragma unroll
    for (int ni = 0; ni < 4; ni++)
#pragma unroll
        for (int i = 0; i < 4; i++)
            ob[(long long)(q * 4 + i) * 512 + ni * 16 + r] = (bf16_t)oacc[ni][i];
}

// ---------------------------------------------------------------------------
// Per-(b,h) transpose of V out of bf16 qkv: Vt[z][d][k] = qkv[b*512+k][1024+h*64+d]
// ---------------------------------------------------------------------------
__global__ __launch_bounds__(256) void transpose_v(
    const bf16_t* __restrict__ qkv, bf16_t* __restrict__ Vt)
{
    int z = blockIdx.x, b = z >> 3, h = z & 7;
    int k0 = blockIdx.y * 64;
    __shared__ bf16_t t[64][72];                 // padded rows: no bank conflicts
    const bf16_t* src = qkv + (long long)(b * 512 + k0) * 1536 + 1024 + h * 64;
    int tid = threadIdx.x;
#pragma unroll
    for (int it = 0; it < 2; it++) {
        int idx = tid + 256 * it;                // 512 chunks of 8 bf16
        int i = idx >> 3, j8 = (idx & 7) << 3;
        bf16x8 v = *(const bf16x8*)(src + (long long)i * 1536 + j8);
#pragma unroll
        for (int j = 0; j < 8; j++) t[i][j8 + j] = v[j];
    }
    __syncthreads();
    bf16_t* dst = Vt + (long long)z * 32768 + k0;
#pragma unroll
    for (int it = 0; it < 2; it++) {
        int idx = tid + 256 * it;
        int d = idx >> 3, kx = (idx & 7) << 3;
        bf16x8 v;
#pragma unroll
        for (int j = 0; j < 8; j++) v[j] = t[kx + j][d];
        *(bf16x8*)(dst + (long long)d * 512 + kx) = v;
    }
}

// ---------------------------------------------------------------------------
// x = LayerNorm(x + rsd) * g + b; also writes bf16 copy of result for GEMMs.
// ---------------------------------------------------------------------------
__global__ __launch_bounds__(256) void add_ln(
    float* __restrict__ x, const float* __restrict__ rsd,
    const float* __restrict__ g, const float* __restrict__ bta,
    bf16_t* __restrict__ xb)
{
    long long row = (long long)blockIdx.x * 4 + (threadIdx.x >> 6);
    int lane = threadIdx.x & 63;
    float4* xr = (float4*)(x + row * 512);
    const float4* rr = (const float4*)(rsd + row * 512);
    float4 s0 = xr[lane], s1 = xr[lane + 64];
    float4 r0 = rr[lane], r1 = rr[lane + 64];
    s0.x += r0.x; s0.y += r0.y; s0.z += r0.z; s0.w += r0.w;
    s1.x += r1.x; s1.y += r1.y; s1.z += r1.z; s1.w += r1.w;
    float sum = s0.x + s0.y + s0.z + s0.w + s1.x + s1.y + s1.z + s1.w;
    float sq  = s0.x*s0.x + s0.y*s0.y + s0.z*s0.z + s0.w*s0.w
              + s1.x*s1.x + s1.y*s1.y + s1.z*s1.z + s1.w*s1.w;
#pragma unroll
    for (int o = 32; o; o >>= 1) { sum += __shfl_xor(sum, o); sq += __shfl_xor(sq, o); }
    float mean = sum * (1.f / 512.f);
    float var  = sq * (1.f / 512.f) - mean * mean;
    float rstd = rsqrtf(var + 1e-5f);
    const float4* g4 = (const float4*)g;
    const float4* b4 = (const float4*)bta;
    float4 gg = g4[lane], bb = b4[lane], o0;
    o0.x = (s0.x - mean) * rstd * gg.x + bb.x;
    o0.y = (s0.y - mean) * rstd * gg.y + bb.y;
    o0.z = (s0.z - mean) * rstd * gg.z + bb.z;
    o0.w = (s0.w - mean) * rstd * gg.w + bb.w;
    xr[lane] = o0;
    bf16x4 h0;
    h0[0] = (bf16_t)o0.x; h0[1] = (bf16_t)o0.y; h0[2] = (bf16_t)o0.z; h0[3] = (bf16_t)o0.w;
    *(bf16x4*)(xb + row * 512 + lane * 4) = h0;
    gg = g4[lane + 64]; bb = b4[lane + 64];
    float4 o1;
    o1.x = (s1.x - mean) * rstd * gg.x + bb.x;
    o1.y = (s1.y - mean) * rstd * gg.y + bb.y;
    o1.z = (s1.z - mean) * rstd * gg.z + bb.z;
    o1.w = (s1.w - mean) * rstd * gg.w + bb.w;
    xr[lane + 64] = o1;
    bf16x4 h1;
    h1[0] = (bf16_t)o1.x; h1[1] = (bf16_t)o1.y; h1[2] = (bf16_t)o1.z; h1[3] = (bf16_t)o1.w;
    *(bf16x4*)(xb + row * 512 + 256 + lane * 4) = h1;
}

// ---------------------------------------------------------------------------
// logits[b][c] = dot(x[b*512], cls_w[c]) + cls_b[c].  64 blocks x 1 wave.
// ---------------------------------------------------------------------------
__global__ void cls_head(const float* __restrict__ x, const float* __restrict__ w,
                         const float* __restrict__ cb, float* __restrict__ out)
{
    int b = blockIdx.x >> 1, c = blockIdx.x & 1;
    int lane = threadIdx.x;
    const float* xr = x + (long long)b * 512 * 512;  // CLS token = b*512
    const float* wr = w + c * 512;
    float s = 0.f;
#pragma unroll
    for (int i = 0; i < 8; i++) s += xr[lane + 64 * i] * wr[lane + 64 * i];
#pragma unroll
    for (int o = 32; o; o >>= 1) s += __shfl_xor(s, o);
    if (lane == 0) out[b * 2 + c] = s + cb[c];
}

// ---------------------------------------------------------------------------
extern "C" void kernel_launch(void* const* d_in, const int* in_sizes, int n_in,
                              void* d_out, int out_size, void* d_ws, size_t ws_size,
                              hipStream_t stream)
{
    const int*   ids   = (const int*)d_in[0];
    const int*   amask = (const int*)d_in[1];
    const float* emb   = (const float*)d_in[2];
    const float* pos   = (const float*)d_in[3];
    const float* in_w  = (const float*)d_in[4];
    const float* in_b  = (const float*)d_in[5];
    const float* out_w = (const float*)d_in[6];
    const float* out_b = (const float*)d_in[7];
    const float* ln1g  = (const float*)d_in[8];
    const float* ln1b  = (const float*)d_in[9];
    const float* ln2g  = (const float*)d_in[10];
    const float* ln2b  = (const float*)d_in[11];
    const float* f1w   = (const float*)d_in[12];
    const float* f1b   = (const float*)d_in[13];
    const float* f2w   = (const float*)d_in[14];
    const float* f2b   = (const float*)d_in[15];
    const float* clsw  = (const float*)d_in[16];
    const float* clsb  = (const float*)d_in[17];

    float* outp = (float*)d_out;
    float* ws = (float*)d_ws;
    // ws layout (float units):
    //   x     fp32 [16384,512]            @ 0          (8,388,608)
    //   xb    bf16 [16384,512]            @ 8,388,608  (4,194,304)
    //   pg    fp32 [16384,512]            @ 12,582,912 (8,388,608)   proj / ffn2 out
    //   Ob    bf16 [16384,512]            @ 20,971,520 (4,194,304)   attn@V out
    //   qkvb  bf16 [16384,1536]           @ 25,165,824 (12,582,912)
    //   Vt    bf16 [256,64,512]           @ 37,748,736 (4,194,304)
    //   fb    bf16 [16384,2048] overlays qkvb+Vt (dead by ffn1 time)
    //   wb    bf16 weights                @ 41,943,040 (4,718,592)
    float*  x    = ws;
    bf16_t* xb   = (bf16_t*)(ws + 8388608);
    float*  pg   = ws + 12582912;
    bf16_t* Ob   = (bf16_t*)(ws + 20971520);
    bf16_t* qkvb = (bf16_t*)(ws + 25165824);
    bf16_t* Vt   = (bf16_t*)(ws + 37748736);
    bf16_t* fb   = qkvb;                       // overlay
    bf16_t* wb   = (bf16_t*)(ws + 41943040);
    bf16_t* w_in  = wb;                        // [3,1536,512]
    bf16_t* w_out = wb + 2359296;              // [3,512,512]
    bf16_t* w_f1  = wb + 3145728;              // [3,2048,512]
    bf16_t* w_f2  = wb + 6291456;              // [3,512,2048]

    // weight conversion (~38 MB read, ~10 us)
    cvt_bf16<<<2304, 256, 0, stream>>>(in_w,  w_in);
    cvt_bf16<<< 768, 256, 0, stream>>>(out_w, w_out);
    cvt_bf16<<<3072, 256, 0, stream>>>(f1w,   w_f1);
    cvt_bf16<<<3072, 256, 0, stream>>>(f2w,   w_f2);

    embed_kernel<<<8192, 256, 0, stream>>>(ids, emb, pos, x, xb);

    for (int l = 0; l < 3; l++) {
        float* attnL = outp + 64 + (long long)l * 67108864;  // [32,8,512,512]

        // qkv = x @ Wqkv^T + b  -> bf16 [16384,1536]
        gemm_m97<0, 1><<<dim3(128, 12, 1), 256, 0, stream>>>(
            xb, w_in + (long long)l * 786432, qkvb, in_b + l * 1536,
            512, 512, 1536, 512, 1.f);

        // Vt[b,h][d][k] (bf16)
        transpose_v<<<dim3(256, 8), 256, 0, stream>>>(qkvb, Vt);

        // fused: scores+softmax -> write P (output) -> P@V -> Ob (bf16)
        attn_fused<<<dim3(8, 256), 256, 0, stream>>>(qkvb, Vt, amask, attnL, Ob);

        // proj = o @ Wout^T + b -> fp32
        gemm_m97<0, 0><<<dim3(128, 4, 1), 256, 0, stream>>>(
            Ob, w_out + (long long)l * 262144, pg, out_b + l * 512,
            512, 512, 512, 512, 1.f);

        // x = LN1(x + proj), write xb
        add_ln<<<4096, 256, 0, stream>>>(x, pg, ln1g + l * 512, ln1b + l * 512, xb);

        // f = gelu(x @ W1^T + b1) -> bf16 [16384,2048]
        gemm_m97<1, 1><<<dim3(128, 16, 1), 256, 0, stream>>>(
            xb, w_f1 + (long long)l * 1048576, fb, f1b + l * 2048,
            512, 512, 2048, 512, 1.f);

        // g = f @ W2^T + b2 -> fp32
        gemm_m97<0, 0><<<dim3(128, 4, 1), 256, 0, stream>>>(
            fb, w_f2 + (long long)l * 1048576, pg, f2b + l * 512,
            2048, 2048, 512, 2048, 1.f);

        // x = LN2(x + g), write xb
        add_ln<<<4096, 256, 0, stream>>>(x, pg, ln2g + l * 512, ln2b + l * 512, xb);
    }

    cls_head<<<64, 64, 0, stream>>>(x, clsw, clsb, outp);
}